// Round 7
// baseline (205.304 us; speedup 1.0000x reference)
//
#include <hip/hip_runtime.h>
#include <math.h>

// Problem dims (fixed by setup_inputs)
#define N_  8
#define C_  4
#define A_  180
#define R_  180
#define NC  (N_*C_)        // 32
#define AR  (A_*R_)        // 32400
#define CAP 1024           // max peaks per (n,c) — expected ~550
#define ROWS_PB 8          // rows per raster block
#define SL  32             // peak slices per row

typedef unsigned long long u64;
typedef unsigned int u32;

// ws layout (bytes) — NOTHING needs pre-zeroing (no global atomics anywhere)
#define OFF_CNT  0                       // u32 cnt[32] (written non-atomically)
#define OFF_PD   128                     // float4 pdata[32][CAP] (512 KB)

// exact reference predicate value at u (u-space; ct2 = |ct|):
// for ct>0, u=x; for ct<0, u=255-x. Bit-exact vs reference since f32 RN is
// negation-symmetric and (x-127.5), (127.5-x) are exact halves.
__device__ __forceinline__ float probe_d(int u, float ct2, float yst, float rp) {
  return __fsub_rn(__fadd_rn(__fmul_rn(__fsub_rn((float)u, 127.5f), ct2), yst), rp);
}

// ---------------------------------------------------------------------------
// Kernel 1 (fused max + tables + peak compaction): ONE block per (n,c).
//  phase 0: LDS trig/rho tables (cos/sin in double, rounded to f32 — matches
//           XLA's correctly-rounded f32 cosf/sinf; r_phys mul-rounded as ref)
//  phase 1: block-wide max of the 32400-elem plane (float4 loads)
//  phase 2: re-scan (L2-hot) for peaks: val > 0.5*max AND no strictly-greater
//           3x3 neighbor (maxpool SAME w/ -inf pad). Wave-aggregated append
//           via LDS counter — no global atomics, so no ws memset needed.
// ---------------------------------------------------------------------------
__global__ __launch_bounds__(256) void peaks_fused_kernel(
    const float* __restrict__ hm,
    const int* __restrict__ Hp, const int* __restrict__ Wp,
    u32* __restrict__ cnt, float4* __restrict__ pdata) {
  int nc  = blockIdx.x;
  int tid = threadIdx.x;
  __shared__ float sct[A_], sst[A_], srp[A_];
  __shared__ float smax[4];
  __shared__ u32 scnt;
  if (tid == 0) scnt = 0;

  int H = Hp[0], W = Wp[0];
  double max_rho = sqrt((double)(W/2)*(double)(W/2) + (double)(H/2)*(double)(H/2));
  float drho = (float)(2.0 * max_rho / (double)(R_ - 1));
  if (tid < A_) {
    // theta = f32(a) * f32(pi/A)  — matches jnp.arange(A,f32)*(np.pi/A)
    float theta = __fmul_rn((float)tid, (float)(3.14159265358979323846 / (double)A_));
    sct[tid] = (float)cos((double)theta);   // correctly-rounded f32
    sst[tid] = (float)sin((double)theta);
    // r_phys = (f32(r) - 89.5) * f32(delta_rho)
    srp[tid] = __fmul_rn(__fsub_rn((float)tid, (float)((R_-1)*0.5)), drho);
  }

  const float*  base = hm + (size_t)nc * AR;
  const float4* p4   = (const float4*)base;      // 8100 float4
  float m = -INFINITY;
  for (int i = tid; i < AR / 4; i += 256) {
    float4 v = p4[i];
    m = fmaxf(fmaxf(m, fmaxf(v.x, v.y)), fmaxf(v.z, v.w));
  }
  for (int off = 32; off; off >>= 1) m = fmaxf(m, __shfl_down(m, off, 64));
  if ((tid & 63) == 0) smax[tid >> 6] = m;
  __syncthreads();
  float thr = 0.5f * fmaxf(fmaxf(smax[0], smax[1]), fmaxf(smax[2], smax[3]));

  for (int idx = tid; idx < AR; idx += 256) {
    float val = base[idx];                       // L2-hot re-read
    bool peak = false;
    int a = 0, r = 0;
    if (val > thr) {                             // ~2% pass
      a = idx / R_; r = idx - a * R_;
      peak = true;
      for (int da = -1; da <= 1 && peak; ++da) {
        int aa = a + da;
        if (aa < 0 || aa >= A_) continue;        // SAME pad with -inf
        for (int dr = -1; dr <= 1; ++dr) {
          if (da == 0 && dr == 0) continue;
          int rr = r + dr;
          if (rr < 0 || rr >= R_) continue;
          if (base[aa * R_ + rr] > val) { peak = false; break; }
        }
      }
    }
    u64 mb = __ballot(peak);
    if (mb) {
      int lane = tid & 63;
      int leader = (int)__ffsll((long long)mb) - 1;
      u32 bslot = 0;
      if (lane == leader) bslot = atomicAdd(&scnt, (u32)__popcll(mb));  // LDS
      bslot = (u32)__shfl((int)bslot, leader, 64);
      if (peak) {
        u32 slot = bslot + (u32)__popcll(mb & ((1ull << lane) - 1ull));
        if (slot < CAP)
          pdata[(size_t)nc * CAP + slot] =
              make_float4(sct[a], sst[a], srp[r], 0.0f);
      }
    }
  }
  __syncthreads();
  if (tid == 0) cnt[nc] = scnt > CAP ? CAP : scnt;   // plain store, no atomic
}

// ---------------------------------------------------------------------------
// Kernel 2: raster. Block = (8-row stripe, nc); 256 thr = 8 rows x 32 slices.
// d(u) monotone non-decreasing in u (ct2>0, RN monotone) -> covered set is
// [u1,u2). Edges: division-guided. For ct2 >= 1e-3 the estimate error
// eps <= 8.4e-5/ct2 + 2e-4 < 0.09 << 0.5, so first-true index is in
// {ceil(q-0.5), +1}: ONE exact probe decides. Else (only a=90, |cos|~4e-8):
// full 9-probe lower_bound (s starts at 256 so the empty answer u=256 is
// reachable — R3 lesson). Per-row OR across 32 slices via shfl_xor tree
// (no LDS atomics), direct float4 tile writeout.
// ---------------------------------------------------------------------------
__global__ __launch_bounds__(256) void raster_kernel(
    const float* __restrict__ mwp,
    const u32* __restrict__ cntg, const float4* __restrict__ pdata,
    float* __restrict__ out) {
  __shared__ u64 rowbits[ROWS_PB][4];       // 256 B
  int yb  = blockIdx.x;                     // row stripe 0..31
  int nc  = blockIdx.y;
  int tid = threadIdx.x;
  int row = tid >> 5;                       // 0..7
  int sub = tid & (SL - 1);                 // 0..31

  int cnt = (int)cntg[nc]; if (cnt > CAP) cnt = CAP;
  const float4* pdg = pdata + (size_t)nc * CAP;

  float mw  = mwp[0];
  float nmw = -mw;
  int   y   = yb * ROWS_PB + row;
  float ycv = __fsub_rn((float)y, 127.5f);

  u64 pm[4] = {0ull, 0ull, 0ull, 0ull};

  for (int i = sub; i < cnt; i += SL) {
    float4 pd = pdg[i];
    float ct = pd.x, st = pd.y, rp = pd.z;
    float ct2 = fabsf(ct);
    float yst = __fmul_rn(ycv, st);
    int u1, u2;
    if (ct2 >= 1e-3f) {
      // approx edges (rounding-mode-free math fine here; exactness comes
      // from the probes)
      float t   = rp - yst;
      float inv = __builtin_amdgcn_rcpf(ct2);          // 1-ulp v_rcp_f32
      float q1  = __fmaf_rn(t - mw, inv, 127.5f);
      float q2  = __fmaf_rn(t + mw, inv, 127.5f);
      q1 = fminf(fmaxf(q1, -2.0f), 260.0f);
      q2 = fminf(fmaxf(q2, -2.0f), 260.0f);
      int k1 = (int)ceilf(q1 - 0.5f); k1 = k1 < 0 ? 0 : (k1 > 255 ? 255 : k1);
      int k2 = (int)ceilf(q2 - 0.5f); k2 = k2 < 0 ? 0 : (k2 > 255 ? 255 : k2);
      float d1 = probe_d(k1, ct2, yst, rp);
      float d2 = probe_d(k2, ct2, yst, rp);
      u1 = k1 + ((d1 > nmw) ? 0 : 1);
      u2 = k2 + ((d2 >= mw) ? 0 : 1);
    } else {
      u1 = 0; u2 = 0;
      #pragma unroll
      for (int s = 256; s; s >>= 1) {
        if (u1 + s <= 256) {
          float d = probe_d(u1 + s - 1, ct2, yst, rp);
          if (!(d > nmw)) u1 += s;
        }
        if (u2 + s <= 256) {
          float d = probe_d(u2 + s - 1, ct2, yst, rp);
          if (!(d >= mw)) u2 += s;
        }
      }
    }
    if (u1 < u2) {                          // covered u in [u1,u2)
      bool neg = ct < 0.0f;                 // map back to x-space
      int xlo = neg ? 256 - u2 : u1;
      int xhi = neg ? 255 - u1 : u2 - 1;
      #pragma unroll
      for (int w = 0; w < 4; ++w) {         // branchless word fold, static idx
        int lo = xlo - (w << 6); lo = lo < 0 ? 0 : lo;
        int hi = xhi - (w << 6); hi = hi > 63 ? 63 : hi;
        if (lo <= hi) pm[w] |= (~0ull >> (63 - hi)) & (~0ull << lo);
      }
    }
  }

  // OR-reduce across the 32 slices of each row (lanes [0,32) / [32,64) are
  // distinct rows; xor masks < 32 stay within a row's lane group)
  #pragma unroll
  for (int m = 1; m < 32; m <<= 1) {
    pm[0] |= __shfl_xor(pm[0], m, 64);
    pm[1] |= __shfl_xor(pm[1], m, 64);
    pm[2] |= __shfl_xor(pm[2], m, 64);
    pm[3] |= __shfl_xor(pm[3], m, 64);
  }
  if (sub < 4) {                            // static-index select, no scratch
    u64 v = (sub == 0) ? pm[0] : (sub == 1) ? pm[1] : (sub == 2) ? pm[2] : pm[3];
    rowbits[row][sub] = v;                  // full overwrite — no zero-init
  }
  __syncthreads();

  // bit -> float tile writeout, float4 coalesced; each pixel written once
  float* otile = out + (size_t)nc * 65536 + (size_t)yb * ROWS_PB * 256;
  for (int j = tid; j < ROWS_PB * 64; j += 256) {   // 64 float4 per row
    int rr = j >> 6, c4 = j & 63;
    u64 wb = rowbits[rr][c4 >> 4];
    int sh = (c4 & 15) * 4;
    float4 v;
    v.x = (float)((wb >> sh) & 1ull);
    v.y = (float)((wb >> (sh + 1)) & 1ull);
    v.z = (float)((wb >> (sh + 2)) & 1ull);
    v.w = (float)((wb >> (sh + 3)) & 1ull);
    ((float4*)(otile + (size_t)rr * 256))[c4] = v;
  }
}

// ---------------------------------------------------------------------------
extern "C" void kernel_launch(void* const* d_in, const int* in_sizes, int n_in,
                              void* d_out, int out_size, void* d_ws, size_t ws_size,
                              hipStream_t stream) {
  const float* hm  = (const float*)d_in[0];   // [8,4,180,180] f32
  const float* mwp = (const float*)d_in[1];   // [1] f32
  const int*   Hp  = (const int*)d_in[2];     // [1] i32
  const int*   Wp  = (const int*)d_in[3];     // [1] i32
  float* out = (float*)d_out;                 // [8,4,256,256] f32

  char* base = (char*)d_ws;
  u32*    cnt  = (u32*)(base + OFF_CNT);
  float4* pdat = (float4*)(base + OFF_PD);

  // NO memset: cnt is plain-stored by kernel 1; pdata beyond cnt is never read.

  peaks_fused_kernel<<<dim3(NC), dim3(256), 0, stream>>>(hm, Hp, Wp, cnt, pdat);

  raster_kernel<<<dim3(32, NC), dim3(256), 0, stream>>>(mwp, cnt, pdat, out);
}

// Round 8
// 45.570 us; speedup vs baseline: 4.5053x; 4.5053x over previous
//
#include <hip/hip_runtime.h>
#include <math.h>

// Problem dims (fixed by setup_inputs)
#define N_  8
#define C_  4
#define A_  180
#define R_  180
#define NC  (N_*C_)        // 32
#define AR  (A_*R_)        // 32400
#define CAP 1024           // max peaks per (n,c) — expected ~550
#define ROWS_PB 8          // rows per raster block
#define SL  32             // peak slices per row

typedef unsigned long long u64;
typedef unsigned int u32;

// ws layout (bytes) — NOTHING pre-zeroed by the host (no fills in the graph).
// cnt is zeroed by prep_kernel's table block (plain stores) before peaks runs.
#define OFF_PMAX 0                       // float pmax[32][8]  (1024 B) plain-stored
#define OFF_CNT  1024                    // u32 cnt[32*32]     (4096 B) one line per nc
#define OFF_TBL  5120                    // float ct[180] st[180] rp[180] (2160 B)
#define OFF_PD   7296                    // float4 pdata[32][CAP] (512 KB) 16B-aligned

// exact reference predicate value at u (u-space; ct2 = |ct|):
// for ct>0, u=x; for ct<0, u=255-x. Bit-exact vs reference since f32 RN is
// negation-symmetric and (x-127.5), (127.5-x) are exact halves.
__device__ __forceinline__ float probe_d(int u, float ct2, float yst, float rp) {
  return __fsub_rn(__fadd_rn(__fmul_rn(__fsub_rn((float)u, 127.5f), ct2), yst), rp);
}

// ---------------------------------------------------------------------------
// Kernel A (prep): grid (9, 32).
//  bx<8 : partial max of plane nc -> pmax[nc][bx] (plain store, no init).
//  bx==8 (nc==0 only): trig/rho tables (cos/sin in double rounded to f32 —
//  matches XLA's correctly-rounded f32 cos/sin; r_phys mul-rounded as ref)
//  AND zeroes the cnt region with plain stores (runs before peaks launches).
// ---------------------------------------------------------------------------
__global__ __launch_bounds__(256) void prep_kernel(
    const float* __restrict__ hm,
    const int* __restrict__ Hp, const int* __restrict__ Wp,
    float* __restrict__ pmax, u32* __restrict__ cnt, float* __restrict__ tbl) {
  int bx = blockIdx.x, nc = blockIdx.y;
  if (bx < 8) {
    const float4* p = (const float4*)(hm + (size_t)nc * AR);  // 8100 float4
    float m = -INFINITY;
    for (int i = bx * 256 + threadIdx.x; i < AR / 4; i += 8 * 256) {
      float4 v = p[i];
      m = fmaxf(fmaxf(m, fmaxf(v.x, v.y)), fmaxf(v.z, v.w));
    }
    // tail elements 32400 = 8100*4 exactly -> no tail
    for (int off = 32; off; off >>= 1) m = fmaxf(m, __shfl_down(m, off, 64));
    __shared__ float sm[4];
    if ((threadIdx.x & 63) == 0) sm[threadIdx.x >> 6] = m;
    __syncthreads();
    if (threadIdx.x == 0)
      pmax[nc * 8 + bx] = fmaxf(fmaxf(sm[0], sm[1]), fmaxf(sm[2], sm[3]));
  } else if (nc == 0) {
    int t = threadIdx.x;
    // zero the whole counter region: 1024 u32 = 4 per thread, plain stores
    #pragma unroll
    for (int k = 0; k < 4; ++k) cnt[k * 256 + t] = 0u;
    int H = Hp[0], W = Wp[0];
    double max_rho = sqrt((double)(W/2)*(double)(W/2) + (double)(H/2)*(double)(H/2));
    float drho = (float)(2.0 * max_rho / (double)(R_ - 1));
    if (t < A_) {
      // theta = f32(a) * f32(pi/A)  — matches jnp.arange(A,f32)*(np.pi/A)
      float theta = __fmul_rn((float)t, (float)(3.14159265358979323846 / (double)A_));
      tbl[t]        = (float)cos((double)theta);   // correctly-rounded f32
      tbl[A_ + t]   = (float)sin((double)theta);
      // r_phys = (f32(r) - 89.5) * f32(delta_rho)
      tbl[2*A_ + t] = __fmul_rn(__fsub_rn((float)t, (float)((R_-1)*0.5)), drho);
    }
  }
}

// ---------------------------------------------------------------------------
// Kernel B: peak detect -> compact EXPANDED list (ct, st, rp) as float4.
// thr from the 8 plain-stored partials (fmax order-robust). ONE atomicAdd per
// wave (aggregated) into cnt[nc*32] (one 128-B line per nc, zeroed by prep).
// peak := hm > 0.5*max AND no 3x3 neighbor strictly greater (== maxpool SAME)
// ---------------------------------------------------------------------------
__global__ __launch_bounds__(256) void peaks_kernel(
    const float* __restrict__ hm, const float* __restrict__ pmax,
    const float* __restrict__ tbl,
    u32* __restrict__ cnt, float4* __restrict__ pdata) {
  int nc  = blockIdx.y;
  int idx = blockIdx.x * 256 + threadIdx.x;   // index within nc
  float m8 = fmaxf(fmaxf(fmaxf(pmax[nc*8+0], pmax[nc*8+1]),
                         fmaxf(pmax[nc*8+2], pmax[nc*8+3])),
                   fmaxf(fmaxf(pmax[nc*8+4], pmax[nc*8+5]),
                         fmaxf(pmax[nc*8+6], pmax[nc*8+7])));
  float thr = 0.5f * m8;
  bool peak = false;
  int a = 0, r = 0;
  if (idx < AR) {
    const float* base = hm + (size_t)nc * AR;
    float val = base[idx];
    if (val > thr) {
      a = idx / R_; r = idx - a * R_;
      peak = true;
      for (int da = -1; da <= 1 && peak; ++da) {
        int aa = a + da;
        if (aa < 0 || aa >= A_) continue;     // SAME pad with -inf
        for (int dr = -1; dr <= 1; ++dr) {
          if (da == 0 && dr == 0) continue;
          int rr = r + dr;
          if (rr < 0 || rr >= R_) continue;
          if (base[aa * R_ + rr] > val) { peak = false; break; }
        }
      }
    }
  }
  u64 mb = __ballot(peak);
  if (mb) {
    int lane = threadIdx.x & 63;
    int leader = (int)__ffsll((long long)mb) - 1;
    u32 bslot = 0;
    if (lane == leader) bslot = atomicAdd(&cnt[nc * 32], (u32)__popcll(mb));
    bslot = (u32)__shfl((int)bslot, leader, 64);
    if (peak) {
      u32 slot = bslot + (u32)__popcll(mb & ((1ull << lane) - 1ull));
      if (slot < CAP)
        pdata[(size_t)nc * CAP + slot] =
            make_float4(tbl[a], tbl[A_ + a], tbl[2 * A_ + r], 0.0f);
    }
  }
}

// ---------------------------------------------------------------------------
// Kernel C: raster. Block = (8-row stripe, nc); 256 thr = 8 rows x 32 slices.
// d(u) monotone non-decreasing in u (ct2>0, RN monotone) -> covered set is
// [u1,u2). Edges: division-guided. For ct2 >= 1e-3 the estimate error
// eps <= 8.4e-5/ct2 + 2e-4 < 0.09 << 0.5, so first-true index is in
// {ceil(q-0.5), +1}: ONE exact probe decides. Else (only a=90, |cos|~4e-8):
// full 9-probe lower_bound (s starts at 256 so the empty answer u=256 is
// reachable — R3 lesson). Per-row OR across 32 slices via shfl_xor tree
// (no LDS atomics), direct float4 tile writeout.
// ---------------------------------------------------------------------------
__global__ __launch_bounds__(256) void raster_kernel(
    const float* __restrict__ mwp,
    const u32* __restrict__ cntg, const float4* __restrict__ pdata,
    float* __restrict__ out) {
  __shared__ u64 rowbits[ROWS_PB][4];       // 256 B
  int yb  = blockIdx.x;                     // row stripe 0..31
  int nc  = blockIdx.y;
  int tid = threadIdx.x;
  int row = tid >> 5;                       // 0..7
  int sub = tid & (SL - 1);                 // 0..31

  int cnt = (int)cntg[nc * 32]; if (cnt > CAP) cnt = CAP;
  const float4* pdg = pdata + (size_t)nc * CAP;

  float mw  = mwp[0];
  float nmw = -mw;
  int   y   = yb * ROWS_PB + row;
  float ycv = __fsub_rn((float)y, 127.5f);

  u64 pm[4] = {0ull, 0ull, 0ull, 0ull};

  for (int i = sub; i < cnt; i += SL) {
    float4 pd = pdg[i];
    float ct = pd.x, st = pd.y, rp = pd.z;
    float ct2 = fabsf(ct);
    float yst = __fmul_rn(ycv, st);
    int u1, u2;
    if (ct2 >= 1e-3f) {
      // approx edges (rounding-mode-free math fine here; exactness comes
      // from the probes)
      float t   = rp - yst;
      float inv = __builtin_amdgcn_rcpf(ct2);          // 1-ulp v_rcp_f32
      float q1  = __fmaf_rn(t - mw, inv, 127.5f);
      float q2  = __fmaf_rn(t + mw, inv, 127.5f);
      q1 = fminf(fmaxf(q1, -2.0f), 260.0f);
      q2 = fminf(fmaxf(q2, -2.0f), 260.0f);
      int k1 = (int)ceilf(q1 - 0.5f); k1 = k1 < 0 ? 0 : (k1 > 255 ? 255 : k1);
      int k2 = (int)ceilf(q2 - 0.5f); k2 = k2 < 0 ? 0 : (k2 > 255 ? 255 : k2);
      float d1 = probe_d(k1, ct2, yst, rp);
      float d2 = probe_d(k2, ct2, yst, rp);
      u1 = k1 + ((d1 > nmw) ? 0 : 1);
      u2 = k2 + ((d2 >= mw) ? 0 : 1);
    } else {
      u1 = 0; u2 = 0;
      #pragma unroll
      for (int s = 256; s; s >>= 1) {
        if (u1 + s <= 256) {
          float d = probe_d(u1 + s - 1, ct2, yst, rp);
          if (!(d > nmw)) u1 += s;
        }
        if (u2 + s <= 256) {
          float d = probe_d(u2 + s - 1, ct2, yst, rp);
          if (!(d >= mw)) u2 += s;
        }
      }
    }
    if (u1 < u2) {                          // covered u in [u1,u2)
      bool neg = ct < 0.0f;                 // map back to x-space
      int xlo = neg ? 256 - u2 : u1;
      int xhi = neg ? 255 - u1 : u2 - 1;
      #pragma unroll
      for (int w = 0; w < 4; ++w) {         // branchless word fold, static idx
        int lo = xlo - (w << 6); lo = lo < 0 ? 0 : lo;
        int hi = xhi - (w << 6); hi = hi > 63 ? 63 : hi;
        if (lo <= hi) pm[w] |= (~0ull >> (63 - hi)) & (~0ull << lo);
      }
    }
  }

  // OR-reduce across the 32 slices of each row (lanes [0,32) / [32,64) are
  // distinct rows; xor masks < 32 stay within a row's lane group)
  #pragma unroll
  for (int m = 1; m < 32; m <<= 1) {
    pm[0] |= __shfl_xor(pm[0], m, 64);
    pm[1] |= __shfl_xor(pm[1], m, 64);
    pm[2] |= __shfl_xor(pm[2], m, 64);
    pm[3] |= __shfl_xor(pm[3], m, 64);
  }
  if (sub < 4) {                            // static-index select, no scratch
    u64 v = (sub == 0) ? pm[0] : (sub == 1) ? pm[1] : (sub == 2) ? pm[2] : pm[3];
    rowbits[row][sub] = v;                  // full overwrite — no zero-init
  }
  __syncthreads();

  // bit -> float tile writeout, float4 coalesced; each pixel written once
  float* otile = out + (size_t)nc * 65536 + (size_t)yb * ROWS_PB * 256;
  for (int j = tid; j < ROWS_PB * 64; j += 256) {   // 64 float4 per row
    int rr = j >> 6, c4 = j & 63;
    u64 wb = rowbits[rr][c4 >> 4];
    int sh = (c4 & 15) * 4;
    float4 v;
    v.x = (float)((wb >> sh) & 1ull);
    v.y = (float)((wb >> (sh + 1)) & 1ull);
    v.z = (float)((wb >> (sh + 2)) & 1ull);
    v.w = (float)((wb >> (sh + 3)) & 1ull);
    ((float4*)(otile + (size_t)rr * 256))[c4] = v;
  }
}

// ---------------------------------------------------------------------------
extern "C" void kernel_launch(void* const* d_in, const int* in_sizes, int n_in,
                              void* d_out, int out_size, void* d_ws, size_t ws_size,
                              hipStream_t stream) {
  const float* hm  = (const float*)d_in[0];   // [8,4,180,180] f32
  const float* mwp = (const float*)d_in[1];   // [1] f32
  const int*   Hp  = (const int*)d_in[2];     // [1] i32
  const int*   Wp  = (const int*)d_in[3];     // [1] i32
  float* out = (float*)d_out;                 // [8,4,256,256] f32

  char* base = (char*)d_ws;
  float*  pmax = (float*)(base + OFF_PMAX);
  u32*    cnt  = (u32*)(base + OFF_CNT);
  float*  tbl  = (float*)(base + OFF_TBL);
  float4* pdat = (float4*)(base + OFF_PD);

  // NO fills in the graph: pmax plain-stored; cnt zeroed inside prep_kernel;
  // pdata beyond cnt never read.

  prep_kernel<<<dim3(9, NC), dim3(256), 0, stream>>>(hm, Hp, Wp, pmax, cnt, tbl);

  peaks_kernel<<<dim3((AR + 255) / 256, NC), dim3(256), 0, stream>>>(
      hm, pmax, tbl, cnt, pdat);

  raster_kernel<<<dim3(32, NC), dim3(256), 0, stream>>>(mwp, cnt, pdat, out);
}